// Round 9
// baseline (896.362 us; speedup 1.0000x reference)
//
#include <hip/hip_runtime.h>
#include <stdint.h>

#define T_DIM 8192
#define D_DIM 2048
#define SCAN_L 128
#define SCAN_C 64

typedef __attribute__((ext_vector_type(8))) __bf16 bf16x8;
typedef __attribute__((ext_vector_type(4))) float f32x4;
typedef __attribute__((ext_vector_type(4))) float f4v;
typedef __attribute__((ext_vector_type(4))) unsigned short us16x4;

__device__ __forceinline__ unsigned short f2bf(float f) {
  union { float f; uint32_t u; } c{f};
  uint32_t u = c.u;
  return (unsigned short)((u + 0x7FFFu + ((u >> 16) & 1u)) >> 16);
}
__device__ __forceinline__ float bf2f(unsigned short h) {
  union { uint32_t u; float f; } c{((uint32_t)h) << 16};
  return c.f;
}
__device__ __forceinline__ float sigmoidf_(float z) {
  return 1.0f / (1.0f + __expf(-z));
}

// ---------------------------------------------------------------------------
// Weight transpose + f32->bf16: W[K][N] f32 -> WT[N][K] bf16
// ---------------------------------------------------------------------------
__global__ void transpose_cvt(const float* __restrict__ W,
                              unsigned short* __restrict__ WT,
                              int K, int N) {
  __shared__ float tile[32][33];
  int n0 = blockIdx.x * 32, k0 = blockIdx.y * 32;
  int tx = threadIdx.x, ty = threadIdx.y;  // 32 x 8
#pragma unroll
  for (int i = 0; i < 4; ++i)
    tile[ty + i * 8][tx] = W[(size_t)(k0 + ty + i * 8) * N + n0 + tx];
  __syncthreads();
#pragma unroll
  for (int i = 0; i < 4; ++i)
    WT[(size_t)(n0 + ty + i * 8) * K + k0 + tx] = f2bf(tile[tx][ty + i * 8]);
}

// ---------------------------------------------------------------------------
// LayerNorm: x f32 [rows][2048] -> out bf16
// ---------------------------------------------------------------------------
__global__ __launch_bounds__(256) void ln_kernel(const float* __restrict__ x,
                                                 const float* __restrict__ g,
                                                 const float* __restrict__ b,
                                                 unsigned short* __restrict__ out) {
  const int D = D_DIM;
  size_t base = (size_t)blockIdx.x * D;
  int tid = threadIdx.x;
  const f4v* xv = reinterpret_cast<const f4v*>(x + base);
  f4v v0 = xv[tid];
  f4v v1 = xv[tid + 256];
  float sum = 0.f, sq = 0.f;
#pragma unroll
  for (int i = 0; i < 4; ++i) {
    sum += v0[i] + v1[i];
    sq += v0[i] * v0[i] + v1[i] * v1[i];
  }
#pragma unroll
  for (int o = 32; o > 0; o >>= 1) {
    sum += __shfl_xor(sum, o);
    sq += __shfl_xor(sq, o);
  }
  __shared__ float red[2][4];
  int wave = tid >> 6, lane = tid & 63;
  if (lane == 0) { red[0][wave] = sum; red[1][wave] = sq; }
  __syncthreads();
  sum = red[0][0] + red[0][1] + red[0][2] + red[0][3];
  sq  = red[1][0] + red[1][1] + red[1][2] + red[1][3];
  float mu = sum * (1.0f / D);
  float rstd = rsqrtf(sq * (1.0f / D) - mu * mu + 1e-5f);
  const f4v* gv = reinterpret_cast<const f4v*>(g);
  const f4v* bv = reinterpret_cast<const f4v*>(b);
  f4v g0 = gv[tid], g1 = gv[tid + 256], b0 = bv[tid], b1 = bv[tid + 256];
  us16x4 o0, o1;
#pragma unroll
  for (int i = 0; i < 4; ++i) {
    o0[i] = f2bf((v0[i] - mu) * rstd * g0[i] + b0[i]);
    o1[i] = f2bf((v1[i] - mu) * rstd * g1[i] + b1[i]);
  }
  us16x4* ov = reinterpret_cast<us16x4*>(out + base);
  ov[tid] = o0;
  ov[tid + 256] = o1;
}

// ---------------------------------------------------------------------------
// Chunked diagonal scan
// ---------------------------------------------------------------------------
__global__ void scan_p1(const unsigned short* __restrict__ u,
                        const float* __restrict__ sdec,
                        float* __restrict__ carry) {
  int d = blockIdx.y * 256 + threadIdx.x;
  int c = blockIdx.x;
  float dec = sigmoidf_(sdec[d]);
  const unsigned short* up = u + (size_t)c * SCAN_L * D_DIM + d;
  float s = 0.f;
#pragma unroll 4
  for (int t = 0; t < SCAN_L; ++t)
    s = fmaf(dec, s, bf2f(up[(size_t)t * D_DIM]));
  carry[c * D_DIM + d] = s;
}

__global__ void scan_p2(const float* __restrict__ carry,
                        const float* __restrict__ sdec,
                        float* __restrict__ init) {
  int d = blockIdx.x * 256 + threadIdx.x;
  float dec = sigmoidf_(sdec[d]);
  float dL = dec;
#pragma unroll
  for (int i = 0; i < 7; ++i) dL *= dL;  // dec^128
  float s = 0.f;
  for (int c = 0; c < SCAN_C; ++c) {
    init[c * D_DIM + d] = s;
    s = fmaf(dL, s, carry[c * D_DIM + d]);
  }
}

__global__ void scan_p3(const unsigned short* __restrict__ u,
                        const unsigned short* __restrict__ gate,
                        const float* __restrict__ init,
                        const float* __restrict__ sdec,
                        unsigned short* __restrict__ stout) {
  int d = blockIdx.y * 256 + threadIdx.x;
  int c = blockIdx.x;
  float dec = sigmoidf_(sdec[d]);
  size_t off = (size_t)c * SCAN_L * D_DIM + d;
  float s = init[c * D_DIM + d];
#pragma unroll 4
  for (int t = 0; t < SCAN_L; ++t) {
    size_t o = off + (size_t)t * D_DIM;
    s = fmaf(dec, s, bf2f(u[o]));
    stout[o] = f2bf(s * bf2f(gate[o]));
  }
}

// ---------------------------------------------------------------------------
// 256x256 GEMM, BK=64, dbuf 128KB LDS, 8 waves (2Mr x 4Nc), with FULL
// one-phase ds_read read-ahead into disjoint register sets:
//   aP = A0 (read in prev tile's ph4), aQ = A1 (read ph2),
//   bF0 = B0 (in-phase ph1, reused ph4), bF1 = B1 (read-ahead ph1).
// Per K-tile (quadrants (0,0),(0,1),(1,1),(1,0)):
//  ph1: read B0,B1(t); stage Ah1(t+1); MFMA(0,0)[aP,bF0]; BAR
//  ph2: read A1(t)->aQ; stage Ah0(t+2); MFMA(0,1)[aP,bF1]; BAR
//  ph3: stage Bh0(t+2); MFMA(1,1)[aQ,bF1]; BAR
//  ph4: stage Bh1(t+2); VM6 (drains t+1's 8, keeps t+2's 6); BARM;
//       read A0(t+1)->aP; MFMA(1,0)[aQ,bF0]  (no closing barrier)
// BARM (asm memory clobber) stops the compiler hoisting the A0(t+1) reads
// above the DMA-visibility barrier. No explicit lgkm waits — the compiler
// inserts exact counted waits; all consumed fragments are >=1 phase old.
// XOR swizzle (slot ^= row&7) via pre-swizzled global source + swizzled read.
// ---------------------------------------------------------------------------
#define STG_(base, dst, bb, hh, kt)                                           \
  {                                                                           \
    __builtin_amdgcn_global_load_lds(                                         \
        (const __attribute__((address_space(1))) uint32_t*)((base) +          \
            (size_t)((hh) * 128) * K + (kt)),                                 \
        (__attribute__((address_space(3))) uint32_t*)((dst) +                 \
            ((bb) * 2 + (hh)) * 8192), 16, 0, 0);                             \
    __builtin_amdgcn_global_load_lds(                                         \
        (const __attribute__((address_space(1))) uint32_t*)((base) +          \
            (size_t)((hh) * 128 + 8) * K + (kt)),                             \
        (__attribute__((address_space(3))) uint32_t*)((dst) +                 \
            ((bb) * 2 + (hh)) * 8192 + 512), 16, 0, 0);                       \
  }

#define LDA_TO(dst, bb, ah)                                                   \
  {                                                                           \
    const unsigned short* p_ = As_ + ((bb) * 2 + (ah)) * 8192 + rA64;         \
    _Pragma("unroll") for (int m_ = 0; m_ < 4; ++m_) {                        \
      dst[m_][0] = *reinterpret_cast<const bf16x8*>(p_ + m_ * 1024 + sw0);    \
      dst[m_][1] = *reinterpret_cast<const bf16x8*>(p_ + m_ * 1024 + sw1);    \
    }                                                                         \
  }

#define LDB_TO(dst, bb, bh)                                                   \
  {                                                                           \
    const unsigned short* p_ = Bs_ + ((bb) * 2 + (bh)) * 8192 + rB64;         \
    _Pragma("unroll") for (int n_ = 0; n_ < 2; ++n_) {                        \
      dst[n_][0] = *reinterpret_cast<const bf16x8*>(p_ + n_ * 1024 + sw0);    \
      dst[n_][1] = *reinterpret_cast<const bf16x8*>(p_ + n_ * 1024 + sw1);    \
    }                                                                         \
  }

#define MFMA_G(aSET, bSET, AH, BH)                                            \
  _Pragma("unroll") for (int m_ = 0; m_ < 4; ++m_)                            \
  _Pragma("unroll") for (int n_ = 0; n_ < 2; ++n_)                            \
  _Pragma("unroll") for (int k_ = 0; k_ < 2; ++k_)                            \
      acc[AH][BH][m_][n_] = __builtin_amdgcn_mfma_f32_16x16x32_bf16(          \
          aSET[m_][k_], bSET[n_][k_], acc[AH][BH][m_][n_], 0, 0, 0);

#define BAR()    __builtin_amdgcn_s_barrier()
#define BARM()   asm volatile("s_barrier" ::: "memory")
#define VM6C()   asm volatile("s_waitcnt vmcnt(6)" ::: "memory")
#define VM0C()   asm volatile("s_waitcnt vmcnt(0)" ::: "memory")
#define PRIO1()  __builtin_amdgcn_s_setprio(1)
#define PRIO0()  __builtin_amdgcn_s_setprio(0)
#define SB0()    __builtin_amdgcn_sched_barrier(0)

#define TILE_(tt, bb)                                                         \
  { /* ph1: quadrant (0,0) */                                                 \
    LDB_TO(bF0, bb, 0);                                                       \
    LDB_TO(bF1, bb, 1);                                                       \
    if ((tt) + 1 < T) STG_(aS, aD, (bb) ^ 1, 1, ((tt) + 1) * 64);             \
    PRIO1(); MFMA_G(aP, bF0, 0, 0); PRIO0();                                  \
    BAR();                                                                    \
    /* ph2: quadrant (0,1) */                                                 \
    LDA_TO(aQ, bb, 1);                                                        \
    if ((tt) + 2 < T) STG_(aS, aD, bb, 0, ((tt) + 2) * 64);                   \
    PRIO1(); MFMA_G(aP, bF1, 0, 1); PRIO0();                                  \
    BAR();                                                                    \
    /* ph3: quadrant (1,1) */                                                 \
    if ((tt) + 2 < T) STG_(bS, bD, bb, 0, ((tt) + 2) * 64);                   \
    PRIO1(); MFMA_G(aQ, bF1, 1, 1); PRIO0();                                  \
    BAR();                                                                    \
    /* ph4: quadrant (1,0); VM6 drains t+1's 8 loads, then prefetch A0' */    \
    if ((tt) + 2 < T) STG_(bS, bD, bb, 1, ((tt) + 2) * 64);                   \
    if ((tt) < T - 2) { VM6C(); } else { VM0C(); }                            \
    BARM();                                                                   \
    if ((tt) + 1 < T) LDA_TO(aP, (bb) ^ 1, 0);                                \
    PRIO1(); MFMA_G(aQ, bF0, 1, 0); PRIO0();                                  \
  }

template <int EPI>  // 0: u/gate split+sigmoid, 1: res+bias f32, 2: silu bf16
__global__ __launch_bounds__(512, 2) void gemm8n(
    const unsigned short* __restrict__ A, const unsigned short* __restrict__ B,
    int M, int N, int K, const float* __restrict__ bias0,
    const float* __restrict__ bias1, const float* __restrict__ res,
    void* __restrict__ out0, void* __restrict__ out1) {
  extern __shared__ unsigned short lds[];
  unsigned short* As_ = lds;          // [2 dbuf][2 half][128][64] = 64KB
  unsigned short* Bs_ = lds + 32768;  // 64KB

  const int tid = threadIdx.x;
  const int w = tid >> 6, l = tid & 63;

  // XCD-aware bijective swizzle (nwg % 8 == 0 for all our shapes)
  const int gx = gridDim.x;
  int lid = blockIdx.y * gx + blockIdx.x;
  int cpx = (gx * gridDim.y) >> 3;
  int swzid = (lid & 7) * cpx + (lid >> 3);
  int tn = swzid % gx, tm = swzid / gx;

  const int mr = w >> 2, nc = w & 3;
  const int lr = l & 15, kq = l >> 4;
  const int l7 = l & 7;

  // staging addresses (pre-swizzled global source, linear LDS dst)
  const int srow = w * 16 + (l >> 3);
  const int csl8 = ((l & 7) ^ (l >> 3)) * 8;
  const unsigned short* aS = A + (size_t)(tm * 256 + srow) * K + csl8;
  const unsigned short* bS = B + (size_t)(tn * 256 + srow) * K + csl8;
  unsigned short* aD = As_ + w * 1024 + l * 8;
  unsigned short* bD = Bs_ + w * 1024 + l * 8;

  // fragment read offsets (ushort units)
  const int rA64 = (mr * 64 + lr) * 64;
  const int rB64 = (nc * 32 + lr) * 64;
  const int sw0 = (kq ^ l7) * 8;
  const int sw1 = ((4 + kq) ^ l7) * 8;

  f32x4 acc[2][2][4][2] = {};
  bf16x8 aP[4][2], aQ[4][2], bF0[2][2], bF1[2][2];

  const int T = K >> 6;  // 64-wide K tiles; T >= 4 and even for all our shapes

  // Prologue: stage tile0's 4 halves + tile1's {Ah0,Bh0,Bh1} (Ah1(t1) comes
  // from ph1 of tile0). VM6 drains tile0's 8; then preload A0(t0).
  STG_(aS, aD, 0, 0, 0);
  STG_(bS, bD, 0, 0, 0);
  STG_(bS, bD, 0, 1, 0);
  STG_(aS, aD, 0, 1, 0);
  SB0();  // pin the 8/6 issue split (vmcnt counting depends on queue order)
  STG_(aS, aD, 1, 0, 64);
  STG_(bS, bD, 1, 0, 64);
  STG_(bS, bD, 1, 1, 64);
  VM6C();
  BARM();
  LDA_TO(aP, 0, 0);

  for (int t2 = 0; t2 < T; t2 += 2) {
    TILE_(t2, 0);
    TILE_(t2 + 1, 1);
  }

  // Epilogue: C row = kq*4 + j (within frag), col = lr
#pragma unroll
  for (int AH = 0; AH < 2; ++AH)
#pragma unroll
    for (int BH = 0; BH < 2; ++BH)
#pragma unroll
      for (int n = 0; n < 2; ++n) {
        int gc = tn * 256 + BH * 128 + nc * 32 + n * 16 + lr;
        if (EPI == 0) {
          bool isU = gc < D_DIM;
          int cc = isU ? gc : gc - D_DIM;
          float bz = isU ? bias0[cc] : bias1[cc];
          unsigned short* uo = (unsigned short*)out0;
          unsigned short* go = (unsigned short*)out1;
#pragma unroll
          for (int m = 0; m < 4; ++m)
#pragma unroll
            for (int j = 0; j < 4; ++j) {
              int gr = tm * 256 + AH * 128 + mr * 64 + m * 16 + kq * 4 + j;
              float v = acc[AH][BH][m][n][j] + bz;
              if (isU) uo[(size_t)gr * D_DIM + cc] = f2bf(v);
              else     go[(size_t)gr * D_DIM + cc] = f2bf(sigmoidf_(v));
            }
        } else if (EPI == 1) {
          float bz = bias0[gc];
          float* oo = (float*)out0;
#pragma unroll
          for (int m = 0; m < 4; ++m)
#pragma unroll
            for (int j = 0; j < 4; ++j) {
              int gr = tm * 256 + AH * 128 + mr * 64 + m * 16 + kq * 4 + j;
              size_t idx = (size_t)gr * N + gc;
              oo[idx] = res[idx] + acc[AH][BH][m][n][j] + bz;
            }
        } else {
          float bz = bias0[gc];
          unsigned short* oo = (unsigned short*)out0;
#pragma unroll
          for (int m = 0; m < 4; ++m)
#pragma unroll
            for (int j = 0; j < 4; ++j) {
              int gr = tm * 256 + AH * 128 + mr * 64 + m * 16 + kq * 4 + j;
              float z = acc[AH][BH][m][n][j] + bz;
              oo[(size_t)gr * N + gc] = f2bf(z * sigmoidf_(z));
            }
        }
      }
}

// ---------------------------------------------------------------------------
// Workspace layout (bytes) — total ~153 MB
// ---------------------------------------------------------------------------
extern "C" void kernel_launch(void* const* d_in, const int* in_sizes, int n_in,
                              void* d_out, int out_size, void* d_ws,
                              size_t ws_size, hipStream_t stream) {
  const float* x      = (const float*)d_in[0];
  const float* ln1g   = (const float*)d_in[1];
  const float* ln1b   = (const float*)d_in[2];
  const float* W_in   = (const float*)d_in[3];
  const float* b_in   = (const float*)d_in[4];
  const float* W_gate = (const float*)d_in[5];
  const float* b_gate = (const float*)d_in[6];
  const float* W_out  = (const float*)d_in[7];
  const float* b_out  = (const float*)d_in[8];
  const float* sdec   = (const float*)d_in[9];
  const float* ln2g   = (const float*)d_in[10];
  const float* ln2b   = (const float*)d_in[11];
  const float* W_ff1  = (const float*)d_in[12];
  const float* b_ff1  = (const float*)d_in[13];
  const float* W_ff2  = (const float*)d_in[14];
  const float* b_ff2  = (const float*)d_in[15];
  float* out = (float*)d_out;

  char* ws = (char*)d_ws;
  unsigned short* WT1    = (unsigned short*)(ws + 0);
  unsigned short* WoutT  = (unsigned short*)(ws + 16777216);
  unsigned short* Wff1T  = (unsigned short*)(ws + 25165824);
  unsigned short* Wff2T  = (unsigned short*)(ws + 41943040);
  unsigned short* R1     = (unsigned short*)(ws + 58720256);   // 32MB
  unsigned short* R2     = (unsigned short*)(ws + 92274688);   // 32MB
  unsigned short* R3     = (unsigned short*)(ws + 125829120);  // 32MB
  float* carry           = (float*)(ws + 159383552);
  float* initb           = (float*)(ws + 159907840);

  unsigned short* hidden = R1;
  unsigned short* ubuf   = R2;
  unsigned short* gbuf   = R3;
  unsigned short* stout  = R1;  // hidden dead after gemm0
  unsigned short* h2     = R3;  // gbuf dead after scan_p3
  unsigned short* abuf   = R1;  // R1+R2 contiguous 64MB; stout/ubuf dead

  hipFuncSetAttribute(reinterpret_cast<const void*>(&gemm8n<0>),
                      hipFuncAttributeMaxDynamicSharedMemorySize, 131072);
  hipFuncSetAttribute(reinterpret_cast<const void*>(&gemm8n<1>),
                      hipFuncAttributeMaxDynamicSharedMemorySize, 131072);
  hipFuncSetAttribute(reinterpret_cast<const void*>(&gemm8n<2>),
                      hipFuncAttributeMaxDynamicSharedMemorySize, 131072);

  dim3 tb(32, 8);
  transpose_cvt<<<dim3(64, 64), tb, 0, stream>>>(W_in, WT1, 2048, 2048);
  transpose_cvt<<<dim3(64, 64), tb, 0, stream>>>(W_gate, WT1 + 2048 * 2048, 2048, 2048);
  transpose_cvt<<<dim3(64, 64), tb, 0, stream>>>(W_out, WoutT, 2048, 2048);
  transpose_cvt<<<dim3(128, 64), tb, 0, stream>>>(W_ff1, Wff1T, 2048, 4096);
  transpose_cvt<<<dim3(64, 128), tb, 0, stream>>>(W_ff2, Wff2T, 4096, 2048);

  ln_kernel<<<T_DIM, 256, 0, stream>>>(x, ln1g, ln1b, hidden);

  gemm8n<0><<<dim3(16, 32), 512, 131072, stream>>>(
      hidden, WT1, T_DIM, 4096, 2048, b_in, b_gate, nullptr, ubuf, gbuf);

  scan_p1<<<dim3(SCAN_C, 8), 256, 0, stream>>>(ubuf, sdec, carry);
  scan_p2<<<8, 256, 0, stream>>>(carry, sdec, initb);
  scan_p3<<<dim3(SCAN_C, 8), 256, 0, stream>>>(ubuf, gbuf, initb, sdec, stout);

  gemm8n<1><<<dim3(8, 32), 512, 131072, stream>>>(
      stout, WoutT, T_DIM, 2048, 2048, b_out, nullptr, x, out, nullptr);

  ln_kernel<<<T_DIM, 256, 0, stream>>>(out, ln2g, ln2b, h2);

  gemm8n<2><<<dim3(16, 32), 512, 131072, stream>>>(
      h2, Wff1T, T_DIM, 4096, 2048, b_ff1, nullptr, nullptr, abuf, nullptr);

  gemm8n<1><<<dim3(8, 32), 512, 131072, stream>>>(
      abuf, Wff2T, T_DIM, 2048, 4096, b_ff2, nullptr, out, out, nullptr);
}

// Round 10
// 592.628 us; speedup vs baseline: 1.5125x; 1.5125x over previous
//
#include <hip/hip_runtime.h>
#include <stdint.h>

#define T_DIM 8192
#define D_DIM 2048
#define SCAN_L 128
#define SCAN_C 64

typedef __attribute__((ext_vector_type(8))) __bf16 bf16x8;
typedef __attribute__((ext_vector_type(4))) float f32x4;
typedef __attribute__((ext_vector_type(4))) float f4v;
typedef __attribute__((ext_vector_type(4))) unsigned short us16x4;

__device__ __forceinline__ unsigned short f2bf(float f) {
  union { float f; uint32_t u; } c{f};
  uint32_t u = c.u;
  return (unsigned short)((u + 0x7FFFu + ((u >> 16) & 1u)) >> 16);
}
__device__ __forceinline__ float bf2f(unsigned short h) {
  union { uint32_t u; float f; } c{((uint32_t)h) << 16};
  return c.f;
}
__device__ __forceinline__ float sigmoidf_(float z) {
  return 1.0f / (1.0f + __expf(-z));
}

// ---------------------------------------------------------------------------
// Weight transpose + f32->bf16: W[K][N] f32 -> WT[N][K] bf16
// ---------------------------------------------------------------------------
__global__ void transpose_cvt(const float* __restrict__ W,
                              unsigned short* __restrict__ WT,
                              int K, int N) {
  __shared__ float tile[32][33];
  int n0 = blockIdx.x * 32, k0 = blockIdx.y * 32;
  int tx = threadIdx.x, ty = threadIdx.y;  // 32 x 8
#pragma unroll
  for (int i = 0; i < 4; ++i)
    tile[ty + i * 8][tx] = W[(size_t)(k0 + ty + i * 8) * N + n0 + tx];
  __syncthreads();
#pragma unroll
  for (int i = 0; i < 4; ++i)
    WT[(size_t)(n0 + ty + i * 8) * K + k0 + tx] = f2bf(tile[tx][ty + i * 8]);
}

// ---------------------------------------------------------------------------
// LayerNorm: x f32 [rows][2048] -> out bf16
// ---------------------------------------------------------------------------
__global__ __launch_bounds__(256) void ln_kernel(const float* __restrict__ x,
                                                 const float* __restrict__ g,
                                                 const float* __restrict__ b,
                                                 unsigned short* __restrict__ out) {
  const int D = D_DIM;
  size_t base = (size_t)blockIdx.x * D;
  int tid = threadIdx.x;
  const f4v* xv = reinterpret_cast<const f4v*>(x + base);
  f4v v0 = xv[tid];
  f4v v1 = xv[tid + 256];
  float sum = 0.f, sq = 0.f;
#pragma unroll
  for (int i = 0; i < 4; ++i) {
    sum += v0[i] + v1[i];
    sq += v0[i] * v0[i] + v1[i] * v1[i];
  }
#pragma unroll
  for (int o = 32; o > 0; o >>= 1) {
    sum += __shfl_xor(sum, o);
    sq += __shfl_xor(sq, o);
  }
  __shared__ float red[2][4];
  int wave = tid >> 6, lane = tid & 63;
  if (lane == 0) { red[0][wave] = sum; red[1][wave] = sq; }
  __syncthreads();
  sum = red[0][0] + red[0][1] + red[0][2] + red[0][3];
  sq  = red[1][0] + red[1][1] + red[1][2] + red[1][3];
  float mu = sum * (1.0f / D);
  float rstd = rsqrtf(sq * (1.0f / D) - mu * mu + 1e-5f);
  const f4v* gv = reinterpret_cast<const f4v*>(g);
  const f4v* bv = reinterpret_cast<const f4v*>(b);
  f4v g0 = gv[tid], g1 = gv[tid + 256], b0 = bv[tid], b1 = bv[tid + 256];
  us16x4 o0, o1;
#pragma unroll
  for (int i = 0; i < 4; ++i) {
    o0[i] = f2bf((v0[i] - mu) * rstd * g0[i] + b0[i]);
    o1[i] = f2bf((v1[i] - mu) * rstd * g1[i] + b1[i]);
  }
  us16x4* ov = reinterpret_cast<us16x4*>(out + base);
  ov[tid] = o0;
  ov[tid + 256] = o1;
}

// ---------------------------------------------------------------------------
// Chunked diagonal scan
// ---------------------------------------------------------------------------
__global__ void scan_p1(const unsigned short* __restrict__ u,
                        const float* __restrict__ sdec,
                        float* __restrict__ carry) {
  int d = blockIdx.y * 256 + threadIdx.x;
  int c = blockIdx.x;
  float dec = sigmoidf_(sdec[d]);
  const unsigned short* up = u + (size_t)c * SCAN_L * D_DIM + d;
  float s = 0.f;
#pragma unroll 4
  for (int t = 0; t < SCAN_L; ++t)
    s = fmaf(dec, s, bf2f(up[(size_t)t * D_DIM]));
  carry[c * D_DIM + d] = s;
}

__global__ void scan_p2(const float* __restrict__ carry,
                        const float* __restrict__ sdec,
                        float* __restrict__ init) {
  int d = blockIdx.x * 256 + threadIdx.x;
  float dec = sigmoidf_(sdec[d]);
  float dL = dec;
#pragma unroll
  for (int i = 0; i < 7; ++i) dL *= dL;  // dec^128
  float s = 0.f;
  for (int c = 0; c < SCAN_C; ++c) {
    init[c * D_DIM + d] = s;
    s = fmaf(dL, s, carry[c * D_DIM + d]);
  }
}

__global__ void scan_p3(const unsigned short* __restrict__ u,
                        const unsigned short* __restrict__ gate,
                        const float* __restrict__ init,
                        const float* __restrict__ sdec,
                        unsigned short* __restrict__ stout) {
  int d = blockIdx.y * 256 + threadIdx.x;
  int c = blockIdx.x;
  float dec = sigmoidf_(sdec[d]);
  size_t off = (size_t)c * SCAN_L * D_DIM + d;
  float s = init[c * D_DIM + d];
#pragma unroll 4
  for (int t = 0; t < SCAN_L; ++t) {
    size_t o = off + (size_t)t * D_DIM;
    s = fmaf(dec, s, bf2f(u[o]));
    stout[o] = f2bf(s * bf2f(gate[o]));
  }
}

// ---------------------------------------------------------------------------
// 256x256 8-phase GEMM (R5 schedule + parity-split B0 read-ahead).
// C[M][N] = A[M][K] * B^T[N][K] (bf16, fp32 acc). 512 thr = 8 waves (2x4).
// Register sets: aF (A, shared), b1 (B1, 1-phase ahead), b0A/b0B (B0 parity
// sets: tile bb consumes b0<bb>, prefetches b0<bb^1> in ph4 BEFORE MFMA(1,0)
// -- no WAR on live operands; ~238 total regs, under the 256 cap).
//  ph1: read B1(t); stage Ah1(t+1); MFMA(0,0)[aF,B0cur]; bar
//  ph2: stage Ah0(t+2); MFMA(0,1)[aF,b1]; read A1(t)->aF; bar
//  ph3: stage Bh0(t+2); MFMA(1,1)[aF,b1]; bar
//  ph4: stage Bh1(t+2); VM6; bar; read B0(t+1)->B0nxt; MFMA(1,0)[aF,B0cur];
//       read A0(t+1)->aF (aF dead after MFMA(1,0))
// VM6 = t+2's 6 loads stay in flight; drains exactly t+1's 8.
// XOR swizzle (slot ^= row&7) via pre-swizzled global source + swizzled read.
// ---------------------------------------------------------------------------
#define STG_(base, dst, bb, hh, kt)                                           \
  {                                                                           \
    __builtin_amdgcn_global_load_lds(                                         \
        (const __attribute__((address_space(1))) uint32_t*)((base) +          \
            (size_t)((hh) * 128) * K + (kt)),                                 \
        (__attribute__((address_space(3))) uint32_t*)((dst) +                 \
            ((bb) * 2 + (hh)) * 8192), 16, 0, 0);                             \
    __builtin_amdgcn_global_load_lds(                                         \
        (const __attribute__((address_space(1))) uint32_t*)((base) +          \
            (size_t)((hh) * 128 + 8) * K + (kt)),                             \
        (__attribute__((address_space(3))) uint32_t*)((dst) +                 \
            ((bb) * 2 + (hh)) * 8192 + 512), 16, 0, 0);                       \
  }

#define LDA_TO(dst, bb, ah)                                                   \
  {                                                                           \
    const unsigned short* p_ = As_ + ((bb) * 2 + (ah)) * 8192 + rA64;         \
    _Pragma("unroll") for (int m_ = 0; m_ < 4; ++m_) {                        \
      dst[m_][0] = *reinterpret_cast<const bf16x8*>(p_ + m_ * 1024 + sw0);    \
      dst[m_][1] = *reinterpret_cast<const bf16x8*>(p_ + m_ * 1024 + sw1);    \
    }                                                                         \
  }

#define LDB_TO(dst, bb, bh)                                                   \
  {                                                                           \
    const unsigned short* p_ = Bs_ + ((bb) * 2 + (bh)) * 8192 + rB64;         \
    _Pragma("unroll") for (int n_ = 0; n_ < 2; ++n_) {                        \
      dst[n_][0] = *reinterpret_cast<const bf16x8*>(p_ + n_ * 1024 + sw0);    \
      dst[n_][1] = *reinterpret_cast<const bf16x8*>(p_ + n_ * 1024 + sw1);    \
    }                                                                         \
  }

#define MFMA_G(aSET, bSET, AH, BH)                                            \
  _Pragma("unroll") for (int m_ = 0; m_ < 4; ++m_)                            \
  _Pragma("unroll") for (int n_ = 0; n_ < 2; ++n_)                            \
  _Pragma("unroll") for (int k_ = 0; k_ < 2; ++k_)                            \
      acc[AH][BH][m_][n_] = __builtin_amdgcn_mfma_f32_16x16x32_bf16(          \
          aSET[m_][k_], bSET[n_][k_], acc[AH][BH][m_][n_], 0, 0, 0);

#define BARRIER() asm volatile("s_barrier" ::: "memory")
#define VM6C()    asm volatile("s_waitcnt vmcnt(6)" ::: "memory")
#define VM0C()    asm volatile("s_waitcnt vmcnt(0)" ::: "memory")
#define PRIO1()   __builtin_amdgcn_s_setprio(1)
#define PRIO0()   __builtin_amdgcn_s_setprio(0)
#define SB0()     __builtin_amdgcn_sched_barrier(0)

#define TILE_(tt, bb, B0C, B0N)                                               \
  { /* ph1 */                                                                 \
    LDB_TO(b1, bb, 1);                                                        \
    if ((tt) + 1 < T) STG_(aS, aD, (bb) ^ 1, 1, ((tt) + 1) * 64);             \
    SB0();                                                                    \
    PRIO1(); MFMA_G(aF, B0C, 0, 0); PRIO0();                                  \
    BARRIER();                                                                \
    /* ph2 */                                                                 \
    if ((tt) + 2 < T) STG_(aS, aD, bb, 0, ((tt) + 2) * 64);                   \
    SB0();                                                                    \
    PRIO1(); MFMA_G(aF, b1, 0, 1); PRIO0();                                   \
    SB0();                                                                    \
    LDA_TO(aF, bb, 1);                                                        \
    BARRIER();                                                                \
    /* ph3 */                                                                 \
    if ((tt) + 2 < T) STG_(bS, bD, bb, 0, ((tt) + 2) * 64);                   \
    SB0();                                                                    \
    PRIO1(); MFMA_G(aF, b1, 1, 1); PRIO0();                                   \
    BARRIER();                                                                \
    /* ph4: drain early; B0(t+1) into other parity set BEFORE MFMA(1,0);     \
       A0(t+1) into aF after (aF dead once MFMA(1,0) issued) */               \
    if ((tt) + 2 < T) STG_(bS, bD, bb, 1, ((tt) + 2) * 64);                   \
    if ((tt) < T - 2) { VM6C(); } else { VM0C(); }                            \
    BARRIER();                                                                \
    SB0();                                                                    \
    if ((tt) + 1 < T) LDB_TO(B0N, (bb) ^ 1, 0);                               \
    SB0();                                                                    \
    PRIO1(); MFMA_G(aF, B0C, 1, 0); PRIO0();                                  \
    SB0();                                                                    \
    if ((tt) + 1 < T) LDA_TO(aF, (bb) ^ 1, 0);                                \
  }

template <int EPI>  // 0: u/gate split+sigmoid, 1: res+bias f32, 2: silu bf16
__global__ __launch_bounds__(512, 2) void gemm8(
    const unsigned short* __restrict__ A, const unsigned short* __restrict__ B,
    int M, int N, int K, const float* __restrict__ bias0,
    const float* __restrict__ bias1, const float* __restrict__ res,
    void* __restrict__ out0, void* __restrict__ out1) {
  extern __shared__ unsigned short lds[];
  unsigned short* As_ = lds;          // [2 dbuf][2 half][128][64] = 64KB
  unsigned short* Bs_ = lds + 32768;  // 64KB

  const int tid = threadIdx.x;
  const int w = tid >> 6, l = tid & 63;

  // XCD-aware bijective swizzle (nwg % 8 == 0 for all our shapes)
  const int gx = gridDim.x;
  int lid = blockIdx.y * gx + blockIdx.x;
  int cpx = (gx * gridDim.y) >> 3;
  int swzid = (lid & 7) * cpx + (lid >> 3);
  int tn = swzid % gx, tm = swzid / gx;

  const int mr = w >> 2, nc = w & 3;
  const int lr = l & 15, kq = l >> 4;
  const int l7 = l & 7;

  // staging addresses (pre-swizzled global source, linear LDS dst)
  const int srow = w * 16 + (l >> 3);
  const int csl8 = ((l & 7) ^ (l >> 3)) * 8;
  const unsigned short* aS = A + (size_t)(tm * 256 + srow) * K + csl8;
  const unsigned short* bS = B + (size_t)(tn * 256 + srow) * K + csl8;
  unsigned short* aD = As_ + w * 1024 + l * 8;
  unsigned short* bD = Bs_ + w * 1024 + l * 8;

  // fragment read offsets (ushort units)
  const int rA64 = (mr * 64 + lr) * 64;
  const int rB64 = (nc * 32 + lr) * 64;
  const int sw0 = (kq ^ l7) * 8;
  const int sw1 = ((4 + kq) ^ l7) * 8;

  f32x4 acc[2][2][4][2] = {};
  bf16x8 aF[4][2], b1[2][2], b0A[2][2], b0B[2][2];

  const int T = K >> 6;  // 64-wide K tiles; T >= 4 and even for all our shapes

  // Prologue: stage tile0's 4 halves + tile1's {Ah0,Bh0,Bh1} (Ah1(t1) comes
  // from ph1 of tile0). VM6 drains tile0's 8; preload A0(t0), B0(t0).
  STG_(aS, aD, 0, 0, 0);
  STG_(bS, bD, 0, 0, 0);
  STG_(bS, bD, 0, 1, 0);
  STG_(aS, aD, 0, 1, 0);
  SB0();  // pin the 8/6 issue split (vmcnt counting depends on queue order)
  STG_(aS, aD, 1, 0, 64);
  STG_(bS, bD, 1, 0, 64);
  STG_(bS, bD, 1, 1, 64);
  VM6C();
  BARRIER();
  SB0();
  LDA_TO(aF, 0, 0);
  LDB_TO(b0A, 0, 0);

  for (int t2 = 0; t2 < T; t2 += 2) {
    TILE_(t2, 0, b0A, b0B);
    TILE_(t2 + 1, 1, b0B, b0A);
  }

  // Epilogue: C row = kq*4 + j (within frag), col = lr
#pragma unroll
  for (int AH = 0; AH < 2; ++AH)
#pragma unroll
    for (int BH = 0; BH < 2; ++BH)
#pragma unroll
      for (int n = 0; n < 2; ++n) {
        int gc = tn * 256 + BH * 128 + nc * 32 + n * 16 + lr;
        if (EPI == 0) {
          bool isU = gc < D_DIM;
          int cc = isU ? gc : gc - D_DIM;
          float bz = isU ? bias0[cc] : bias1[cc];
          unsigned short* uo = (unsigned short*)out0;
          unsigned short* go = (unsigned short*)out1;
#pragma unroll
          for (int m = 0; m < 4; ++m)
#pragma unroll
            for (int j = 0; j < 4; ++j) {
              int gr = tm * 256 + AH * 128 + mr * 64 + m * 16 + kq * 4 + j;
              float v = acc[AH][BH][m][n][j] + bz;
              if (isU) uo[(size_t)gr * D_DIM + cc] = f2bf(v);
              else     go[(size_t)gr * D_DIM + cc] = f2bf(sigmoidf_(v));
            }
        } else if (EPI == 1) {
          float bz = bias0[gc];
          float* oo = (float*)out0;
#pragma unroll
          for (int m = 0; m < 4; ++m)
#pragma unroll
            for (int j = 0; j < 4; ++j) {
              int gr = tm * 256 + AH * 128 + mr * 64 + m * 16 + kq * 4 + j;
              size_t idx = (size_t)gr * N + gc;
              oo[idx] = res[idx] + acc[AH][BH][m][n][j] + bz;
            }
        } else {
          float bz = bias0[gc];
          unsigned short* oo = (unsigned short*)out0;
#pragma unroll
          for (int m = 0; m < 4; ++m)
#pragma unroll
            for (int j = 0; j < 4; ++j) {
              int gr = tm * 256 + AH * 128 + mr * 64 + m * 16 + kq * 4 + j;
              float z = acc[AH][BH][m][n][j] + bz;
              oo[(size_t)gr * N + gc] = f2bf(z * sigmoidf_(z));
            }
        }
      }
}

// ---------------------------------------------------------------------------
// Workspace layout (bytes) — total ~153 MB
// ---------------------------------------------------------------------------
extern "C" void kernel_launch(void* const* d_in, const int* in_sizes, int n_in,
                              void* d_out, int out_size, void* d_ws,
                              size_t ws_size, hipStream_t stream) {
  const float* x      = (const float*)d_in[0];
  const float* ln1g   = (const float*)d_in[1];
  const float* ln1b   = (const float*)d_in[2];
  const float* W_in   = (const float*)d_in[3];
  const float* b_in   = (const float*)d_in[4];
  const float* W_gate = (const float*)d_in[5];
  const float* b_gate = (const float*)d_in[6];
  const float* W_out  = (const float*)d_in[7];
  const float* b_out  = (const float*)d_in[8];
  const float* sdec   = (const float*)d_in[9];
  const float* ln2g   = (const float*)d_in[10];
  const float* ln2b   = (const float*)d_in[11];
  const float* W_ff1  = (const float*)d_in[12];
  const float* b_ff1  = (const float*)d_in[13];
  const float* W_ff2  = (const float*)d_in[14];
  const float* b_ff2  = (const float*)d_in[15];
  float* out = (float*)d_out;

  char* ws = (char*)d_ws;
  unsigned short* WT1    = (unsigned short*)(ws + 0);
  unsigned short* WoutT  = (unsigned short*)(ws + 16777216);
  unsigned short* Wff1T  = (unsigned short*)(ws + 25165824);
  unsigned short* Wff2T  = (unsigned short*)(ws + 41943040);
  unsigned short* R1     = (unsigned short*)(ws + 58720256);   // 32MB
  unsigned short* R2     = (unsigned short*)(ws + 92274688);   // 32MB
  unsigned short* R3     = (unsigned short*)(ws + 125829120);  // 32MB
  float* carry           = (float*)(ws + 159383552);
  float* initb           = (float*)(ws + 159907840);

  unsigned short* hidden = R1;
  unsigned short* ubuf   = R2;
  unsigned short* gbuf   = R3;
  unsigned short* stout  = R1;  // hidden dead after gemm0
  unsigned short* h2     = R3;  // gbuf dead after scan_p3
  unsigned short* abuf   = R1;  // R1+R2 contiguous 64MB; stout/ubuf dead

  hipFuncSetAttribute(reinterpret_cast<const void*>(&gemm8<0>),
                      hipFuncAttributeMaxDynamicSharedMemorySize, 131072);
  hipFuncSetAttribute(reinterpret_cast<const void*>(&gemm8<1>),
                      hipFuncAttributeMaxDynamicSharedMemorySize, 131072);
  hipFuncSetAttribute(reinterpret_cast<const void*>(&gemm8<2>),
                      hipFuncAttributeMaxDynamicSharedMemorySize, 131072);

  dim3 tb(32, 8);
  transpose_cvt<<<dim3(64, 64), tb, 0, stream>>>(W_in, WT1, 2048, 2048);
  transpose_cvt<<<dim3(64, 64), tb, 0, stream>>>(W_gate, WT1 + 2048 * 2048, 2048, 2048);
  transpose_cvt<<<dim3(64, 64), tb, 0, stream>>>(W_out, WoutT, 2048, 2048);
  transpose_cvt<<<dim3(128, 64), tb, 0, stream>>>(W_ff1, Wff1T, 2048, 4096);
  transpose_cvt<<<dim3(64, 128), tb, 0, stream>>>(W_ff2, Wff2T, 4096, 2048);

  ln_kernel<<<T_DIM, 256, 0, stream>>>(x, ln1g, ln1b, hidden);

  gemm8<0><<<dim3(16, 32), 512, 131072, stream>>>(
      hidden, WT1, T_DIM, 4096, 2048, b_in, b_gate, nullptr, ubuf, gbuf);

  scan_p1<<<dim3(SCAN_C, 8), 256, 0, stream>>>(ubuf, sdec, carry);
  scan_p2<<<8, 256, 0, stream>>>(carry, sdec, initb);
  scan_p3<<<dim3(SCAN_C, 8), 256, 0, stream>>>(ubuf, gbuf, initb, sdec, stout);

  gemm8<1><<<dim3(8, 32), 512, 131072, stream>>>(
      stout, WoutT, T_DIM, 2048, 2048, b_out, nullptr, x, out, nullptr);

  ln_kernel<<<T_DIM, 256, 0, stream>>>(out, ln2g, ln2b, h2);

  gemm8<2><<<dim3(16, 32), 512, 131072, stream>>>(
      h2, Wff1T, T_DIM, 4096, 2048, b_ff1, nullptr, nullptr, abuf, nullptr);

  gemm8<1><<<dim3(8, 32), 512, 131072, stream>>>(
      abuf, Wff2T, T_DIM, 2048, 4096, b_ff2, nullptr, out, out, nullptr);
}